// Round 1
// baseline (124.115 us; speedup 1.0000x reference)
//
#include <hip/hip_runtime.h>
#include <math.h>

// Tropical (max-plus) depthwise conv2d, 5x5, stride 1, pad 2, dilation 1.
// x: (8,32,224,224) f32, kernel: (32,1,5,5) f32, out: (8,32,224,224) f32.
// out[b,c,h,w] = max_{i,j} x[b,c,h-2+i, w-2+j] + kernel[c,0,4-i,4-j]

#define TC_B 8
#define TC_C 32
#define TC_H 224
#define TC_W 224
#define TC_WQ (TC_W / 4)   // 56 float4 per row

__global__ __launch_bounds__(256) void tropical_conv2d_kernel(
    const float* __restrict__ x, const float* __restrict__ kern,
    float* __restrict__ out) {
  // block: (64,4). threadIdx.x = wq (0..63, active <56), threadIdx.y = local row.
  // grid: B*C*(H/4) blocks. blockIdx.x -> (bc, hgroup)
  const int wq = threadIdx.x;
  const int hl = threadIdx.y;
  const int blk = blockIdx.x;
  const int hgroup = blk % (TC_H / 4);
  const int bc = blk / (TC_H / 4);        // 0..255 (b*C + c)
  const int c = bc % TC_C;
  const int h = hgroup * 4 + hl;

  // Stage flipped kernel into LDS: wk[i*5+j] = kern[c*25 + 24 - (i*5+j)]
  __shared__ float wk[25];
  const int t = hl * 64 + wq;
  if (t < 25) wk[t] = kern[c * 25 + 24 - t];
  __syncthreads();

  if (wq >= TC_WQ) return;

  const float* xp = x + (size_t)bc * (TC_H * TC_W);
  const float NEG = -INFINITY;

  float acc0 = NEG, acc1 = NEG, acc2 = NEG, acc3 = NEG;

  #pragma unroll
  for (int i = 0; i < 5; ++i) {
    const int r = h - 2 + i;
    if (r < 0 || r >= TC_H) continue;
    const float4* row = (const float4*)(xp + (size_t)r * TC_W);
    float4 a, b, cc;
    if (wq > 0)        a  = row[wq - 1];
    else               a  = make_float4(NEG, NEG, NEG, NEG);
    b = row[wq];
    if (wq < TC_WQ - 1) cc = row[wq + 1];
    else                cc = make_float4(NEG, NEG, NEG, NEG);

    // v[k] = input column wq*4 - 4 + k, k in [0,12)
    float v[12] = {a.x, a.y, a.z, a.w, b.x, b.y, b.z, b.w, cc.x, cc.y, cc.z, cc.w};

    // output col o (0..3) uses v[2+o+j], j in [0,5), weight wk[i*5+j]
    #pragma unroll
    for (int j = 0; j < 5; ++j) {
      const float w = wk[i * 5 + j];
      acc0 = fmaxf(acc0, v[2 + j] + w);
      acc1 = fmaxf(acc1, v[3 + j] + w);
      acc2 = fmaxf(acc2, v[4 + j] + w);
      acc3 = fmaxf(acc3, v[5 + j] + w);
    }
  }

  float4 res = make_float4(acc0, acc1, acc2, acc3);
  ((float4*)(out + (size_t)bc * (TC_H * TC_W) + (size_t)h * TC_W))[wq] = res;
}

extern "C" void kernel_launch(void* const* d_in, const int* in_sizes, int n_in,
                              void* d_out, int out_size, void* d_ws, size_t ws_size,
                              hipStream_t stream) {
  const float* x = (const float*)d_in[0];
  const float* k = (const float*)d_in[1];
  float* out = (float*)d_out;

  dim3 block(64, 4, 1);
  dim3 grid(TC_B * TC_C * (TC_H / 4), 1, 1);
  tropical_conv2d_kernel<<<grid, block, 0, stream>>>(x, k, out);
}

// Round 2
// 121.394 us; speedup vs baseline: 1.0224x; 1.0224x over previous
//
#include <hip/hip_runtime.h>
#include <math.h>

// Tropical (max-plus) depthwise conv2d, 5x5, stride 1, pad 2, dilation 1.
// x: (8,32,224,224) f32, kernel: (32,1,5,5) f32, out: (8,32,224,224) f32.
// out[b,c,h,w] = max_{i,j} x[b,c,h-2+i, w-2+j] + kernel[c,0,4-i,4-j]
//
// R2: 4 output rows per thread (16 outputs) — 8 input rows loaded once each
// into registers, reused across output rows. max3-friendly reduction trees.

#define TC_B 8
#define TC_C 32
#define TC_H 224
#define TC_W 224
#define TC_WQ (TC_W / 4)    // 56 float4 per row
#define TC_HG (TC_H / 16)   // 14 row-groups of 16

__global__ __launch_bounds__(256) void tropical_conv2d_kernel(
    const float* __restrict__ x, const float* __restrict__ kern,
    float* __restrict__ out) {
  const int wq = threadIdx.x;   // 0..63, active < 56
  const int hl = threadIdx.y;   // 0..3 (wave-uniform: one wave per y-row)
  const int blk = blockIdx.x;
  const int hg = blk % TC_HG;
  const int bc = blk / TC_HG;   // b*C + c
  const int c = bc % TC_C;

  // Flipped kernel -> LDS: wk[i*5+j] = wflip[i][j] = kern[c][4-i][4-j]
  __shared__ float wk[25];
  const int t = hl * 64 + wq;
  if (t < 25) wk[t] = kern[c * 25 + 24 - t];
  __syncthreads();

  if (wq >= TC_WQ) return;

  const int hbase = hg * 16 + hl * 4;      // first of this thread's 4 output rows
  const float* xp = x + (size_t)bc * (TC_H * TC_W);
  const float NEG = -INFINITY;

  float acc[4][4];
  #pragma unroll
  for (int o = 0; o < 4; ++o)
    #pragma unroll
    for (int k = 0; k < 4; ++k) acc[o][k] = NEG;

  #pragma unroll
  for (int ri = 0; ri < 8; ++ri) {
    const int r = hbase + ri - 2;          // input row (wave-uniform validity)
    float v[12];
    if (r >= 0 && r < TC_H) {
      const float4* row = (const float4*)(xp + (size_t)r * TC_W);
      float4 b = row[wq];
      float4 a, cc;
      if (wq > 0)          a  = row[wq - 1];
      else                 a  = make_float4(NEG, NEG, NEG, NEG);
      if (wq < TC_WQ - 1)  cc = row[wq + 1];
      else                 cc = make_float4(NEG, NEG, NEG, NEG);
      v[0]=a.x; v[1]=a.y; v[2]=a.z; v[3]=a.w;
      v[4]=b.x; v[5]=b.y; v[6]=b.z; v[7]=b.w;
      v[8]=cc.x; v[9]=cc.y; v[10]=cc.z; v[11]=cc.w;
    } else {
      #pragma unroll
      for (int q = 0; q < 12; ++q) v[q] = NEG;
    }

    // input row r contributes to output row o with weight row i = ri - o
    #pragma unroll
    for (int o = 0; o < 4; ++o) {
      const int i = ri - o;
      if (i < 0 || i > 4) continue;        // resolved at compile time
      const float w0 = wk[i * 5 + 0];
      const float w1 = wk[i * 5 + 1];
      const float w2 = wk[i * 5 + 2];
      const float w3 = wk[i * 5 + 3];
      const float w4 = wk[i * 5 + 4];
      #pragma unroll
      for (int k = 0; k < 4; ++k) {
        const float t0 = v[2 + k] + w0;
        const float t1 = v[3 + k] + w1;
        const float t2 = v[4 + k] + w2;
        const float t3 = v[5 + k] + w3;
        const float t4 = v[6 + k] + w4;
        // tree shape -> v_max3_f32: max3(t0,t1, max3(t2,t3,t4)) then max w/ acc
        const float m = fmaxf(fmaxf(t0, t1), fmaxf(fmaxf(t2, t3), t4));
        acc[o][k] = fmaxf(acc[o][k], m);
      }
    }
  }

  float* op = out + (size_t)bc * (TC_H * TC_W);
  #pragma unroll
  for (int o = 0; o < 4; ++o) {
    ((float4*)(op + (size_t)(hbase + o) * TC_W))[wq] =
        make_float4(acc[o][0], acc[o][1], acc[o][2], acc[o][3]);
  }
}

extern "C" void kernel_launch(void* const* d_in, const int* in_sizes, int n_in,
                              void* d_out, int out_size, void* d_ws, size_t ws_size,
                              hipStream_t stream) {
  const float* x = (const float*)d_in[0];
  const float* k = (const float*)d_in[1];
  float* out = (float*)d_out;

  dim3 block(64, 4, 1);
  dim3 grid(TC_B * TC_C * TC_HG, 1, 1);
  tropical_conv2d_kernel<<<grid, block, 0, stream>>>(x, k, out);
}

// Round 3
// 114.809 us; speedup vs baseline: 1.0811x; 1.0574x over previous
//
#include <hip/hip_runtime.h>
#include <math.h>

// Tropical (max-plus) depthwise conv2d, 5x5, stride 1, pad 2, dilation 1.
// x: (8,32,224,224) f32, kernel: (32,1,5,5) f32, out: (8,32,224,224) f32.
// out[b,c,h,w] = max_{i,j} x[b,c,h-2+i, w-2+j] + kernel[c,0,4-i,4-j]
//
// R3: cooperative LDS tile staging (fixes global-load-latency serialization
// seen in R1/R2: VGPR=12, compiler serialized loads). Halo pre-filled with
// -inf -> branch-free compute. Weights via wave-uniform scalar loads.

#define TC_B 8
#define TC_C 32
#define TC_H 224
#define TC_W 224
#define TC_WQ (TC_W / 4)      // 56 float4 per row
#define TC_HG (TC_H / 16)     // 14 row-groups of 16
#define T_ROWS 20             // 16 output rows + 2 halo each side
#define T_STRIDE 240          // floats per tile row: 4 halo | 224 data | 12 pad
#define T_F4_PER_ROW 56       // data float4s per row

__global__ __launch_bounds__(256) void tropical_conv2d_kernel(
    const float* __restrict__ x, const float* __restrict__ kern,
    float* __restrict__ out) {
  const int wq = threadIdx.x;   // 0..63, active < 56 for compute
  const int hl = threadIdx.y;   // 0..3
  const int blk = blockIdx.x;
  const int hg = blk % TC_HG;
  const int bc = blk / TC_HG;   // b*C + c  (wave-uniform)
  const int c = bc % TC_C;

  __shared__ float tile[T_ROWS * T_STRIDE];   // 19200 B

  const float NEG = -INFINITY;
  const float4 NINF4 = make_float4(NEG, NEG, NEG, NEG);
  const int t = hl * 64 + wq;                 // flat 0..255
  const int row0 = hg * 16 - 2;               // x-row of tile row 0
  const float* xp = x + (size_t)bc * (TC_H * TC_W);

  // --- halo columns: tile f4-index 0 (cols 0..3) and 57 (cols 228..231) ---
  if (t < 40) {
    const int r = t % T_ROWS;
    const int cf = (t < T_ROWS) ? 0 : 57;
    *(float4*)&tile[r * T_STRIDE + cf * 4] = NINF4;
  }

  // --- stage 20 rows x 56 float4 (coalesced, independent loads) ---
  #pragma unroll
  for (int k = 0; k < 5; ++k) {
    const int idx = t + k * 256;              // 0..1279
    if (idx < T_ROWS * T_F4_PER_ROW) {        // < 1120
      const int r = idx / T_F4_PER_ROW;
      const int cf = idx % T_F4_PER_ROW;
      const int ir = row0 + r;
      float4 val;
      if (ir >= 0 && ir < TC_H)
        val = ((const float4*)(xp + (size_t)ir * TC_W))[cf];
      else
        val = NINF4;
      *(float4*)&tile[r * T_STRIDE + (1 + cf) * 4] = val;
    }
  }

  // --- weights: wave-uniform address -> scalar loads into SGPRs ---
  // w[i*5+j] = wflip[i][j] = kern[c][4-i][4-j]
  float w[25];
  #pragma unroll
  for (int q = 0; q < 25; ++q) w[q] = kern[c * 25 + 24 - q];

  __syncthreads();

  if (wq >= TC_WQ) return;

  float acc[4][4];
  #pragma unroll
  for (int o = 0; o < 4; ++o)
    #pragma unroll
    for (int k = 0; k < 4; ++k) acc[o][k] = NEG;

  // thread's output rows: h = hg*16 + hl*4 + o, o in 0..3
  // input tile rows used: hl*4 + ri, ri in 0..7; weight row i = ri - o
  #pragma unroll
  for (int ri = 0; ri < 8; ++ri) {
    const float* rp = &tile[(hl * 4 + ri) * T_STRIDE + 4 * wq];
    const float4 A = *(const float4*)(rp);
    const float4 Bv = *(const float4*)(rp + 4);
    const float4 Cv = *(const float4*)(rp + 8);
    // v[m] = tile col 4wq+m = x col 4wq-4+m
    float v[12] = {A.x, A.y, A.z, A.w, Bv.x, Bv.y, Bv.z, Bv.w,
                   Cv.x, Cv.y, Cv.z, Cv.w};

    #pragma unroll
    for (int o = 0; o < 4; ++o) {
      const int i = ri - o;
      if (i < 0 || i > 4) continue;           // compile-time resolved
      #pragma unroll
      for (int k = 0; k < 4; ++k) {
        const float t0 = v[2 + k + 0] + w[i * 5 + 0];
        const float t1 = v[2 + k + 1] + w[i * 5 + 1];
        const float t2 = v[2 + k + 2] + w[i * 5 + 2];
        const float t3 = v[2 + k + 3] + w[i * 5 + 3];
        const float t4 = v[2 + k + 4] + w[i * 5 + 4];
        // 6-value max as 2x v_max3 + 1 v_max
        acc[o][k] = fmaxf(fmaxf(fmaxf(acc[o][k], t0), t1),
                          fmaxf(fmaxf(t2, t3), t4));
      }
    }
  }

  float* op = out + (size_t)bc * (TC_H * TC_W) + (size_t)(hg * 16 + hl * 4) * TC_W;
  #pragma unroll
  for (int o = 0; o < 4; ++o) {
    ((float4*)(op + (size_t)o * TC_W))[wq] =
        make_float4(acc[o][0], acc[o][1], acc[o][2], acc[o][3]);
  }
}

extern "C" void kernel_launch(void* const* d_in, const int* in_sizes, int n_in,
                              void* d_out, int out_size, void* d_ws, size_t ws_size,
                              hipStream_t stream) {
  const float* x = (const float*)d_in[0];
  const float* k = (const float*)d_in[1];
  float* out = (float*)d_out;

  dim3 block(64, 4, 1);
  dim3 grid(TC_B * TC_C * TC_HG, 1, 1);
  tropical_conv2d_kernel<<<grid, block, 0, stream>>>(x, k, out);
}